// Round 5
// baseline (165.637 us; speedup 1.0000x reference)
//
#include <hip/hip_runtime.h>
#include <math.h>

#define EPSF 1e-6f
#define RPW 4   // rays per wave; block = 4 waves = 16 rays

__device__ __forceinline__ float rl(float v, int srclane) {
    return __uint_as_float(__builtin_amdgcn_readlane(__float_as_uint(v), srclane));
}

// single-pass LN stats over 64 lanes: one 6-step dual shuffle chain
__device__ __forceinline__ void ln_stats(float a, float& mu, float& rstd) {
    float s1 = a, s2 = a * a;
#pragma unroll
    for (int off = 32; off > 0; off >>= 1) {
        s1 += __shfl_xor(s1, off, 64);
        s2 += __shfl_xor(s2, off, 64);
    }
    mu = s1 * (1.0f / 64.0f);
    float var = fmaxf(s2 * (1.0f / 64.0f) - mu * mu, 0.0f);
    rstd = rsqrtf(var + EPSF);
}

__device__ __forceinline__ float wave_sum64(float v) {
#pragma unroll
    for (int off = 32; off > 0; off >>= 1) v += __shfl_xor(v, off, 64);
    return v;
}

// posenc element e in [0,126): [plucker(6) | sin(2^j*x_i) j=0..9 | sin(2^j*x_i+pi/2) j=0..9]
__device__ __forceinline__ float posenc_elem(const float* pl, int e) {
    if (e < 6) return pl[e];
    int t = e - 6;
    int j = t / 6;
    int i = t - j * 6;
    int jm = (j < 10) ? j : (j - 10);
    float arg = pl[i] * (float)(1 << jm);
    if (j >= 10) arg += 1.5707963705062866f;  // f32(pi/2), matches ref
    return sinf(arg);
}

// ws layout (f32), ALL TRANSPOSED [m][n] (m-major) for LDS-friendly forward reads:
//   [0 .. K*8192)            : W0_T[k][m*64+n], m in [0,128), rows 126,127 zeroed
//   [offW .. offW+K*7*4096)  : Wl_T[k][l-1][m*64+n]
//   [offB .. offB+K*8*64)    : b_eff[k][l][n]
// K == 2 assumed (reference setup); blocks handle both k to halve w_W traffic.
__global__ __launch_bounds__(128) void precompute_kernel(
    const float* __restrict__ latent_tokens, const float* __restrict__ token_embeddings,
    const float* __restrict__ h_W0, const float* __restrict__ h_b0,
    const float* __restrict__ h_ln_s0, const float* __restrict__ h_ln_b0,
    const float* __restrict__ w_W0, const float* __restrict__ w_b0,
    const float* __restrict__ bb_W0, const float* __restrict__ bb_b0,
    const float* __restrict__ h_W, const float* __restrict__ h_b,
    const float* __restrict__ h_ln_s, const float* __restrict__ h_ln_b,
    const float* __restrict__ w_W, const float* __restrict__ w_b,
    const float* __restrict__ bb_W, const float* __restrict__ bb_b,
    float* __restrict__ ws, int offW, int offB)
{
    const int s = blockIdx.x;    // column-slice 0..31
    const int l = blockIdx.y;    // 0..7
    const int tid = threadIdx.x; // 0..127
    const int lane = tid & 63;
    const int warp = tid >> 6;   // 0..1 -> k

    __shared__ float s_chunk[2][128];
    __shared__ float s_h[2][64];

#pragma unroll
    for (int t = tid; t < 256; t += 128) {
        int k = t >> 7, m = t & 127;
        s_chunk[k][m] = (m < 64) ? latent_tokens[(k * 8 + l) * 64 + m]
                                 : token_embeddings[l * 64 + (m - 64)];
    }
    __syncthreads();

    const float* hW  = (l == 0) ? h_W0    : h_W    + (size_t)(l - 1) * 128 * 64;
    const float* hb  = (l == 0) ? h_b0    : h_b    + (l - 1) * 64;
    const float* hls = (l == 0) ? h_ln_s0 : h_ln_s + (l - 1) * 64;
    const float* hlb = (l == 0) ? h_ln_b0 : h_ln_b + (l - 1) * 64;

    {   // wave `warp` computes h for k = warp
        float a = hb[lane];
#pragma unroll 16
        for (int m = 0; m < 128; m++) a += s_chunk[warp][m] * hW[m * 64 + lane];
        float mu, rstd;
        ln_stats(a, mu, rstd);
        s_h[warp][lane] = fmaxf((a - mu) * rstd * hls[lane] + hlb[lane], 0.0f);
    }
    __syncthreads();

    const int n_in  = (l == 0) ? 126 : 64;
    const int nflat = 64 * n_in;
    const int slice = nflat / 32;        // 252 or 128
    const float* wW = (l == 0) ? w_W0 : w_W + (size_t)(l - 1) * 64 * 4096;
    const float* wb = (l == 0) ? w_b0 : w_b + (size_t)(l - 1) * 4096;

    for (int o = s * slice + tid; o < s * slice + slice; o += 128) {
        float wbv = wb[o];
        float a0 = wbv, a1 = wbv;
#pragma unroll 16
        for (int j = 0; j < 64; j++) {
            float w = wW[(size_t)j * nflat + o];
            a0 += s_h[0][j] * w;
            a1 += s_h[1][j] * w;
        }
        int n = o / n_in, m = o - n * n_in;
        if (l == 0) {
            ws[m * 64 + n] = a0;
            ws[8192 + m * 64 + n] = a1;
        } else {
            float* base = ws + offW + (size_t)(l - 1) * 4096;
            base[m * 64 + n] = a0;
            base[7 * 4096 + m * 64 + n] = a1;
        }
    }

    if (l == 0 && s == 0) {              // zero pad rows m=126,127 for both k
        ws[8064 + tid] = 0.0f;
        ws[8192 + 8064 + tid] = 0.0f;
    }

    if (s == 0) {                        // b_eff: warp -> k
        const float* bW  = (l == 0) ? bb_W0 : bb_W + (size_t)(l - 1) * 64 * 64;
        const float* bb_ = (l == 0) ? bb_b0 : bb_b + (l - 1) * 64;
        float a = bb_[lane];
#pragma unroll 16
        for (int j = 0; j < 64; j++) a += s_h[warp][j] * bW[j * 64 + lane];
        ws[offB + (warp * 8 + l) * 64 + lane] = a;
    }
}

// Block = 256 thr (4 waves), 16 rays/block, RPW=4 per wave; lane = neuron.
// Weights staged per-layer in a 64KB LDS 4-buffer rotation; layer0 = buffers 0+1.
// Pipeline per iter l: write staged l+1 -> LDS, issue loads for l+2, barrier, compute l.
__global__ __launch_bounds__(256) void forward_kernel(
    const float* __restrict__ rays,
    const float* __restrict__ ln_s0, const float* __restrict__ ln_b0,
    const float* __restrict__ ln_s, const float* __restrict__ ln_b,
    const float* __restrict__ rgb_W, const float* __restrict__ rgb_b,
    const float* __restrict__ ws, int offW, int offB,
    float* __restrict__ out, int K, int P)
{
    __shared__ float Lds[16384];         // 4 buffers x 4096 f32 = 64 KB
    const int tid  = threadIdx.x;
    const int warp = tid >> 6;
    const int lane = tid & 63;
    const int total = K * P;
    const int base = blockIdx.x * (4 * RPW);
    const int k = base / P;              // uniform per block (P % 16 == 0)
    const int r0 = base + warp * RPW;

    const float4* gW0 = (const float4*)(ws + (size_t)k * 8192);
    const float4* gWL = (const float4*)(ws + offW + (size_t)k * 7 * 4096);

    // prologue: issue layer1 loads, stage layer0, write layer1, issue layer2 loads
    float4 pf[4];
#pragma unroll
    for (int it = 0; it < 4; it++) pf[it] = gWL[tid + it * 256];
#pragma unroll
    for (int it = 0; it < 8; it++) ((float4*)Lds)[tid + it * 256] = gW0[tid + it * 256];

    // posenc for RPW rays (VALU work overlaps the staging loads)
    float net0[RPW], net1[RPW];
#pragma unroll
    for (int q = 0; q < RPW; q++) {
        int r = r0 + q; if (r > total - 1) r = total - 1;
        float o0 = rays[r * 6 + 0], o1 = rays[r * 6 + 1], o2 = rays[r * 6 + 2];
        float d0 = rays[r * 6 + 3], d1 = rays[r * 6 + 4], d2 = rays[r * 6 + 5];
        float pl[6];
        pl[0] = d0; pl[1] = d1; pl[2] = d2;
        pl[3] = o1 * d2 - o2 * d1;
        pl[4] = o2 * d0 - o0 * d2;
        pl[5] = o0 * d1 - o1 * d0;
        net0[q] = posenc_elem(pl, lane);
        net1[q] = (lane + 64 < 126) ? posenc_elem(pl, lane + 64) : 0.0f;
    }

#pragma unroll
    for (int it = 0; it < 4; it++) ((float4*)(Lds + 2 * 4096))[tid + it * 256] = pf[it]; // layer1 -> LB2
#pragma unroll
    for (int it = 0; it < 4; it++) pf[it] = gWL[1024 + tid + it * 256];                  // layer2
    __syncthreads();

    float acc[RPW];
    {   // layer 0: 128 m over Lds[0..8191]
        float bia = ws[offB + (k * 8 + 0) * 64 + lane];
        float pre[RPW];
#pragma unroll
        for (int q = 0; q < RPW; q++) pre[q] = bia;
#pragma unroll
        for (int m = 0; m < 64; m++) {
            float wv = Lds[m * 64 + lane];
#pragma unroll
            for (int q = 0; q < RPW; q++) pre[q] += rl(net0[q], m) * wv;
        }
#pragma unroll
        for (int m = 0; m < 64; m++) {
            float wv = Lds[(m + 64) * 64 + lane];
#pragma unroll
            for (int q = 0; q < RPW; q++) pre[q] += rl(net1[q], m) * wv;
        }
        float sc = ln_s0[lane], bc = ln_b0[lane];
#pragma unroll
        for (int q = 0; q < RPW; q++) {
            float mu, rstd;
            ln_stats(pre[q], mu, rstd);
            acc[q] = fmaxf((pre[q] - mu) * rstd * sc + bc, 0.0f);
        }
    }

    // layers 1..7: compute l reads LB[(l+1)&3]; write target(l+1)=LB[(l+2)&3]
#pragma unroll 1
    for (int l = 1; l < 8; l++) {
        if (l < 7) {
            float* dst = Lds + (size_t)(((l + 2) & 3)) * 4096;
#pragma unroll
            for (int it = 0; it < 4; it++) ((float4*)dst)[tid + it * 256] = pf[it];
            if (l < 6) {
#pragma unroll
                for (int it = 0; it < 4; it++) pf[it] = gWL[(size_t)(l + 1) * 1024 + tid + it * 256];
            }
        }
        __syncthreads();
        const float* B = Lds + (size_t)((l + 1) & 3) * 4096;
        float bia = ws[offB + (k * 8 + l) * 64 + lane];
        float na[RPW];
#pragma unroll
        for (int q = 0; q < RPW; q++) na[q] = bia;
#pragma unroll
        for (int m = 0; m < 64; m++) {
            float wv = B[m * 64 + lane];
#pragma unroll
            for (int q = 0; q < RPW; q++) na[q] += rl(acc[q], m) * wv;
        }
        float sc = ln_s[(l - 1) * 64 + lane], bc = ln_b[(l - 1) * 64 + lane];
#pragma unroll
        for (int q = 0; q < RPW; q++) {
            float mu, rstd;
            ln_stats(na[q], mu, rstd);
            acc[q] = fmaxf((na[q] - mu) * rstd * sc + bc, 0.0f);
        }
    }

    // rgb head: rgb_W is (64,3) row-major
    float w0 = rgb_W[lane * 3 + 0], w1 = rgb_W[lane * 3 + 1], w2 = rgb_W[lane * 3 + 2];
    float b0 = rgb_b[0], b1 = rgb_b[1], b2 = rgb_b[2];
#pragma unroll
    for (int q = 0; q < RPW; q++) {
        float c0 = wave_sum64(acc[q] * w0);
        float c1 = wave_sum64(acc[q] * w1);
        float c2 = wave_sum64(acc[q] * w2);
        if (lane == 0 && r0 + q < total) {
            out[(r0 + q) * 3 + 0] = 1.0f / (1.0f + expf(-(c0 + b0)));
            out[(r0 + q) * 3 + 1] = 1.0f / (1.0f + expf(-(c1 + b1)));
            out[(r0 + q) * 3 + 2] = 1.0f / (1.0f + expf(-(c2 + b2)));
        }
    }
}

extern "C" void kernel_launch(void* const* d_in, const int* in_sizes, int n_in,
                              void* d_out, int out_size, void* d_ws, size_t ws_size,
                              hipStream_t stream) {
    const float* rays    = (const float*)d_in[0];
    const float* latent  = (const float*)d_in[1];
    const float* tok_emb = (const float*)d_in[2];
    const float* h_W0    = (const float*)d_in[3];
    const float* h_b0    = (const float*)d_in[4];
    const float* h_ln_s0 = (const float*)d_in[5];
    const float* h_ln_b0 = (const float*)d_in[6];
    const float* w_W0    = (const float*)d_in[7];
    const float* w_b0    = (const float*)d_in[8];
    const float* bb_W0   = (const float*)d_in[9];
    const float* bb_b0   = (const float*)d_in[10];
    const float* ln_s0   = (const float*)d_in[11];
    const float* ln_b0   = (const float*)d_in[12];
    const float* h_W     = (const float*)d_in[13];
    const float* h_b     = (const float*)d_in[14];
    const float* h_ln_s  = (const float*)d_in[15];
    const float* h_ln_b  = (const float*)d_in[16];
    const float* w_W     = (const float*)d_in[17];
    const float* w_b     = (const float*)d_in[18];
    const float* bb_W    = (const float*)d_in[19];
    const float* bb_b    = (const float*)d_in[20];
    const float* ln_s    = (const float*)d_in[21];
    const float* ln_b    = (const float*)d_in[22];
    const float* rgb_W   = (const float*)d_in[23];
    const float* rgb_b   = (const float*)d_in[24];
    float* out = (float*)d_out;

    const int K = in_sizes[1] / (8 * 64);      // latent_tokens (K,8,64); K==2 in dataset
    const int P = in_sizes[0] / (6 * K);       // rays (K,P,6)
    const int offW = K * 8192;                 // f32 elements (W0_T padded to 128 rows)
    const int offB = offW + K * 7 * 4096;

    float* ws = (float*)d_ws;

    dim3 pgrid(32, 8);
    precompute_kernel<<<pgrid, 128, 0, stream>>>(
        latent, tok_emb, h_W0, h_b0, h_ln_s0, h_ln_b0, w_W0, w_b0, bb_W0, bb_b0,
        h_W, h_b, h_ln_s, h_ln_b, w_W, w_b, bb_W, bb_b, ws, offW, offB);

    const int total = K * P;
    const int rays_per_block = 4 * RPW;        // 16
    const int blocks = (total + rays_per_block - 1) / rays_per_block;
    forward_kernel<<<blocks, 256, 0, stream>>>(
        rays, ln_s0, ln_b0, ln_s, ln_b, rgb_W, rgb_b,
        ws, offW, offB, out, K, P);
}

// Round 6
// 157.713 us; speedup vs baseline: 1.0502x; 1.0502x over previous
//
#include <hip/hip_runtime.h>
#include <math.h>

#define EPSF 1e-6f
#define RPW 4   // rays per wave

__device__ __forceinline__ float rl(float v, int srclane) {
    return __uint_as_float(__builtin_amdgcn_readlane(__float_as_uint(v), srclane));
}

// single-pass LN stats over 64 lanes: one 6-step dual shuffle chain
__device__ __forceinline__ void ln_stats(float a, float& mu, float& rstd) {
    float s1 = a, s2 = a * a;
#pragma unroll
    for (int off = 32; off > 0; off >>= 1) {
        s1 += __shfl_xor(s1, off, 64);
        s2 += __shfl_xor(s2, off, 64);
    }
    mu = s1 * (1.0f / 64.0f);
    float var = fmaxf(s2 * (1.0f / 64.0f) - mu * mu, 0.0f);
    rstd = rsqrtf(var + EPSF);
}

__device__ __forceinline__ float wave_sum64(float v) {
#pragma unroll
    for (int off = 32; off > 0; off >>= 1) v += __shfl_xor(v, off, 64);
    return v;
}

// posenc element e in [0,126): [plucker(6) | sin(2^j*x_i) j=0..9 | sin(2^j*x_i+pi/2) j=0..9]
__device__ __forceinline__ float posenc_elem(const float* pl, int e) {
    if (e < 6) return pl[e];
    int t = e - 6;
    int j = t / 6;
    int i = t - j * 6;
    int jm = (j < 10) ? j : (j - 10);
    float arg = pl[i] * (float)(1 << jm);
    if (j >= 10) arg += 1.5707963705062866f;  // f32(pi/2), matches ref
    return sinf(arg);
}

// ws layout (f32), NATURAL [n][m] layout (lane = n reads its own contiguous row):
//   [0 .. K*8192)            : W0[k][n*128+m], m in [0,126), cols 126,127 zeroed
//   [offW .. offW+K*7*4096)  : Wl[k][l-1][n*64+m]
//   [offB .. offB+K*8*64)    : b_eff[k][l][n]
// K == 2 (reference setup); each block computes both k to halve w_W traffic.
__global__ __launch_bounds__(128) void precompute_kernel(
    const float* __restrict__ latent_tokens, const float* __restrict__ token_embeddings,
    const float* __restrict__ h_W0, const float* __restrict__ h_b0,
    const float* __restrict__ h_ln_s0, const float* __restrict__ h_ln_b0,
    const float* __restrict__ w_W0, const float* __restrict__ w_b0,
    const float* __restrict__ bb_W0, const float* __restrict__ bb_b0,
    const float* __restrict__ h_W, const float* __restrict__ h_b,
    const float* __restrict__ h_ln_s, const float* __restrict__ h_ln_b,
    const float* __restrict__ w_W, const float* __restrict__ w_b,
    const float* __restrict__ bb_W, const float* __restrict__ bb_b,
    float* __restrict__ ws, int offW, int offB)
{
    const int s = blockIdx.x;    // column-slice 0..31
    const int l = blockIdx.y;    // 0..7
    const int tid = threadIdx.x; // 0..127
    const int lane = tid & 63;
    const int warp = tid >> 6;   // 0..1 -> k

    __shared__ float s_chunk[2][128];
    __shared__ float s_h[2][64];

#pragma unroll
    for (int t = tid; t < 256; t += 128) {
        int k = t >> 7, m = t & 127;
        s_chunk[k][m] = (m < 64) ? latent_tokens[(k * 8 + l) * 64 + m]
                                 : token_embeddings[l * 64 + (m - 64)];
    }
    __syncthreads();

    const float* hW  = (l == 0) ? h_W0    : h_W    + (size_t)(l - 1) * 128 * 64;
    const float* hb  = (l == 0) ? h_b0    : h_b    + (l - 1) * 64;
    const float* hls = (l == 0) ? h_ln_s0 : h_ln_s + (l - 1) * 64;
    const float* hlb = (l == 0) ? h_ln_b0 : h_ln_b + (l - 1) * 64;

    {   // wave `warp` computes h for k = warp
        float a = hb[lane];
#pragma unroll 16
        for (int m = 0; m < 128; m++) a += s_chunk[warp][m] * hW[m * 64 + lane];
        float mu, rstd;
        ln_stats(a, mu, rstd);
        s_h[warp][lane] = fmaxf((a - mu) * rstd * hls[lane] + hlb[lane], 0.0f);
    }
    __syncthreads();

    const int n_in  = (l == 0) ? 126 : 64;
    const int nflat = 64 * n_in;
    const int slice = nflat / 32;        // 252 or 128
    const float* wW = (l == 0) ? w_W0 : w_W + (size_t)(l - 1) * 64 * 4096;
    const float* wb = (l == 0) ? w_b0 : w_b + (size_t)(l - 1) * 4096;

    for (int o = s * slice + tid; o < s * slice + slice; o += 128) {
        float wbv = wb[o];
        float a0 = wbv, a1 = wbv;
#pragma unroll 16
        for (int j = 0; j < 64; j++) {
            float w = wW[(size_t)j * nflat + o];
            a0 += s_h[0][j] * w;
            a1 += s_h[1][j] * w;
        }
        int n = o / n_in, m = o - n * n_in;
        if (l == 0) {
            ws[n * 128 + m] = a0;
            ws[8192 + n * 128 + m] = a1;
        } else {
            float* base = ws + offW + (size_t)(l - 1) * 4096;
            base[n * 64 + m] = a0;
            base[7 * 4096 + n * 64 + m] = a1;
        }
    }

    if (l == 0 && s == 0) {              // zero cols m=126,127 of every n-row, both k
        int n = tid >> 1, c = tid & 1;
        ws[n * 128 + 126 + c] = 0.0f;
        ws[8192 + n * 128 + 126 + c] = 0.0f;
    }

    if (s == 0) {                        // b_eff: warp -> k
        const float* bW  = (l == 0) ? bb_W0 : bb_W + (size_t)(l - 1) * 64 * 64;
        const float* bb_ = (l == 0) ? bb_b0 : bb_b + (l - 1) * 64;
        float a = bb_[lane];
#pragma unroll 16
        for (int j = 0; j < 64; j++) a += s_h[warp][j] * bW[j * 64 + lane];
        ws[offB + (warp * 8 + l) * 64 + lane] = a;
    }
}

// One wave = RPW rays; lane = neuron. No LDS, no barriers.
// Weights stream through a 4-deep float4 ring (fully unrolled -> registers),
// every load issued 4 chunks (~160 cyc of MAC work) before its use.
__global__ __launch_bounds__(256) void forward_kernel(
    const float* __restrict__ rays,
    const float* __restrict__ ln_s0, const float* __restrict__ ln_b0,
    const float* __restrict__ ln_s, const float* __restrict__ ln_b,
    const float* __restrict__ rgb_W, const float* __restrict__ rgb_b,
    const float* __restrict__ ws, int offW, int offB,
    float* __restrict__ out, int K, int P)
{
    const int warp = threadIdx.x >> 6;
    const int lane = threadIdx.x & 63;
    const int total = K * P;
    const int r0 = (blockIdx.x * 4 + warp) * RPW;
    if (r0 >= total) return;            // whole-wave exit
    const int k = r0 / P;               // uniform per wave (P % 16 == 0)

    const float* W0row  = ws + (size_t)k * 8192 + lane * 128;           // this lane's layer-0 row
    const float* WLrow  = ws + offW + (size_t)k * 7 * 4096 + lane * 64; // layer-1 row; +4096/layer

    // start the weight pipeline FIRST: chunks 0..3 of layer 0
    float4 buf[4];
#pragma unroll
    for (int c = 0; c < 4; c++) buf[c] = ((const float4*)W0row)[c];

    // posenc for RPW rays (sinf VALU work overlaps the loads above)
    float net0[RPW], net1[RPW];
#pragma unroll
    for (int q = 0; q < RPW; q++) {
        int r = r0 + q; if (r > total - 1) r = total - 1;
        float o0 = rays[r * 6 + 0], o1 = rays[r * 6 + 1], o2 = rays[r * 6 + 2];
        float d0 = rays[r * 6 + 3], d1 = rays[r * 6 + 4], d2 = rays[r * 6 + 5];
        float pl[6];
        pl[0] = d0; pl[1] = d1; pl[2] = d2;
        pl[3] = o1 * d2 - o2 * d1;
        pl[4] = o2 * d0 - o0 * d2;
        pl[5] = o0 * d1 - o1 * d0;
        net0[q] = posenc_elem(pl, lane);
        net1[q] = (lane + 64 < 126) ? posenc_elem(pl, lane + 64) : 0.0f;
    }

    float acc[RPW];

    {   // layer 0: 32 chunks (m = 0..127, cols 126/127 are zero)
        float bia = ws[offB + (k * 8 + 0) * 64 + lane];
        float pre[RPW];
#pragma unroll
        for (int q = 0; q < RPW; q++) pre[q] = bia;
#pragma unroll
        for (int c = 0; c < 32; c++) {
            float4 cur = buf[c & 3];
            // prefetch: chunks c+4 of layer 0, tail switches to layer 1 chunks 0..3
            buf[c & 3] = (c < 28) ? ((const float4*)W0row)[c + 4]
                                  : ((const float4*)WLrow)[c - 28];
            float wj[4] = {cur.x, cur.y, cur.z, cur.w};
#pragma unroll
            for (int j = 0; j < 4; j++) {
                int m = c * 4 + j;
#pragma unroll
                for (int q = 0; q < RPW; q++)
                    pre[q] += ((m < 64) ? rl(net0[q], m) : rl(net1[q], m - 64)) * wj[j];
            }
        }
        float sc = ln_s0[lane], bc = ln_b0[lane];
#pragma unroll
        for (int q = 0; q < RPW; q++) {
            float mu, rstd;
            ln_stats(pre[q], mu, rstd);
            acc[q] = fmaxf((pre[q] - mu) * rstd * sc + bc, 0.0f);
        }
    }

    // layers 1..7: fully unrolled; buf holds layer l's chunks 0..3 on entry
#pragma unroll
    for (int l = 1; l < 8; l++) {
        const float* row  = WLrow + (size_t)(l - 1) * 4096;
        const float* nrow = (l < 7) ? row + 4096 : row;   // l=7: dummy re-read (L1-hot)
        float bia = ws[offB + (k * 8 + l) * 64 + lane];
        float na[RPW];
#pragma unroll
        for (int q = 0; q < RPW; q++) na[q] = bia;
#pragma unroll
        for (int c = 0; c < 16; c++) {
            float4 cur = buf[c & 3];
            buf[c & 3] = (c < 12) ? ((const float4*)row)[c + 4]
                                  : ((const float4*)nrow)[c - 12];
            float wj[4] = {cur.x, cur.y, cur.z, cur.w};
#pragma unroll
            for (int j = 0; j < 4; j++) {
                int m = c * 4 + j;
#pragma unroll
                for (int q = 0; q < RPW; q++) na[q] += rl(acc[q], m) * wj[j];
            }
        }
        float sc = ln_s[(l - 1) * 64 + lane], bc = ln_b[(l - 1) * 64 + lane];
#pragma unroll
        for (int q = 0; q < RPW; q++) {
            float mu, rstd;
            ln_stats(na[q], mu, rstd);
            acc[q] = fmaxf((na[q] - mu) * rstd * sc + bc, 0.0f);
        }
    }

    // rgb head: rgb_W is (64,3) row-major
    float w0 = rgb_W[lane * 3 + 0], w1 = rgb_W[lane * 3 + 1], w2 = rgb_W[lane * 3 + 2];
    float b0 = rgb_b[0], b1 = rgb_b[1], b2 = rgb_b[2];
#pragma unroll
    for (int q = 0; q < RPW; q++) {
        float c0 = wave_sum64(acc[q] * w0);
        float c1 = wave_sum64(acc[q] * w1);
        float c2 = wave_sum64(acc[q] * w2);
        if (lane == 0 && r0 + q < total) {
            out[(r0 + q) * 3 + 0] = 1.0f / (1.0f + expf(-(c0 + b0)));
            out[(r0 + q) * 3 + 1] = 1.0f / (1.0f + expf(-(c1 + b1)));
            out[(r0 + q) * 3 + 2] = 1.0f / (1.0f + expf(-(c2 + b2)));
        }
    }
}

extern "C" void kernel_launch(void* const* d_in, const int* in_sizes, int n_in,
                              void* d_out, int out_size, void* d_ws, size_t ws_size,
                              hipStream_t stream) {
    const float* rays    = (const float*)d_in[0];
    const float* latent  = (const float*)d_in[1];
    const float* tok_emb = (const float*)d_in[2];
    const float* h_W0    = (const float*)d_in[3];
    const float* h_b0    = (const float*)d_in[4];
    const float* h_ln_s0 = (const float*)d_in[5];
    const float* h_ln_b0 = (const float*)d_in[6];
    const float* w_W0    = (const float*)d_in[7];
    const float* w_b0    = (const float*)d_in[8];
    const float* bb_W0   = (const float*)d_in[9];
    const float* bb_b0   = (const float*)d_in[10];
    const float* ln_s0   = (const float*)d_in[11];
    const float* ln_b0   = (const float*)d_in[12];
    const float* h_W     = (const float*)d_in[13];
    const float* h_b     = (const float*)d_in[14];
    const float* h_ln_s  = (const float*)d_in[15];
    const float* h_ln_b  = (const float*)d_in[16];
    const float* w_W     = (const float*)d_in[17];
    const float* w_b     = (const float*)d_in[18];
    const float* bb_W    = (const float*)d_in[19];
    const float* bb_b    = (const float*)d_in[20];
    const float* ln_s    = (const float*)d_in[21];
    const float* ln_b    = (const float*)d_in[22];
    const float* rgb_W   = (const float*)d_in[23];
    const float* rgb_b   = (const float*)d_in[24];
    float* out = (float*)d_out;

    const int K = in_sizes[1] / (8 * 64);      // latent_tokens (K,8,64); K==2 in dataset
    const int P = in_sizes[0] / (6 * K);       // rays (K,P,6)
    const int offW = K * 8192;                 // f32 elements (W0 rows padded to 128 cols)
    const int offB = offW + K * 7 * 4096;

    float* ws = (float*)d_ws;

    dim3 pgrid(32, 8);
    precompute_kernel<<<pgrid, 128, 0, stream>>>(
        latent, tok_emb, h_W0, h_b0, h_ln_s0, h_ln_b0, w_W0, w_b0, bb_W0, bb_b0,
        h_W, h_b, h_ln_s, h_ln_b, w_W, w_b, bb_W, bb_b, ws, offW, offB);

    const int total = K * P;
    const int rays_per_block = 4 * RPW;        // 16
    const int blocks = (total + rays_per_block - 1) / rays_per_block;
    forward_kernel<<<blocks, 256, 0, stream>>>(
        rays, ln_s0, ln_b0, ln_s, ln_b, rgb_W, rgb_b,
        ws, offW, offB, out, K, P);
}

// Round 8
// 142.998 us; speedup vs baseline: 1.1583x; 1.1029x over previous
//
#include <hip/hip_runtime.h>
#include <math.h>

#define EPSF 1e-6f
typedef unsigned int uint;
typedef _Float16 f16x2 __attribute__((ext_vector_type(2)));
typedef __fp16 h16x2 __attribute__((ext_vector_type(2)));

__device__ __forceinline__ uint rlu(uint v, int srclane) {
    return (uint)__builtin_amdgcn_readlane((int)v, srclane);
}

__device__ __forceinline__ float dot2u(uint w, uint a, float c) {
#if __has_builtin(__builtin_amdgcn_fdot2)
    return __builtin_amdgcn_fdot2(__builtin_bit_cast(f16x2, w),
                                  __builtin_bit_cast(f16x2, a), c, false);
#else
    f16x2 wv = __builtin_bit_cast(f16x2, w), av = __builtin_bit_cast(f16x2, a);
    return c + (float)wv.x * (float)wv.x + (float)wv.y * (float)av.y;
#endif
}

__device__ __forceinline__ uint pkact(float lo, float hi) {
#if __has_builtin(__builtin_amdgcn_cvt_pkrtz)
    h16x2 p = __builtin_amdgcn_cvt_pkrtz(lo, hi);
    return __builtin_bit_cast(uint, p);
#else
    f16x2 p; p.x = (_Float16)lo; p.y = (_Float16)hi;
    return __builtin_bit_cast(uint, p);
#endif
}

__device__ __forceinline__ float bpermf(int byteaddr, float v) {
    return __int_as_float(__builtin_amdgcn_ds_bpermute(byteaddr, __float_as_int(v)));
}

// single-pass LN stats over 64 lanes
__device__ __forceinline__ void ln_stats(float a, float& mu, float& rstd) {
    float s1 = a, s2 = a * a;
#pragma unroll
    for (int off = 32; off > 0; off >>= 1) {
        s1 += __shfl_xor(s1, off, 64);
        s2 += __shfl_xor(s2, off, 64);
    }
    mu = s1 * (1.0f / 64.0f);
    float var = fmaxf(s2 * (1.0f / 64.0f) - mu * mu, 0.0f);
    rstd = rsqrtf(var + EPSF);
}

__device__ __forceinline__ float wave_sum64(float v) {
#pragma unroll
    for (int off = 32; off > 0; off >>= 1) v += __shfl_xor(v, off, 64);
    return v;
}

// posenc element e in [0,126)
__device__ __forceinline__ float posenc_elem(const float* pl, int e) {
    if (e < 6) return pl[e];
    int t = e - 6;
    int j = t / 6;
    int i = t - j * 6;
    int jm = (j < 10) ? j : (j - 10);
    float arg = pl[i] * (float)(1 << jm);
    if (j >= 10) arg += 1.5707963705062866f;
    return sinf(arg);
}

// ws layout (BYTES), K==2:
//   [0 .. 32768)        : W0 f16 [k][n*128 + m], m in [0,126), m=126,127 zeroed  (16 KB/k)
//   [32768 .. 147456)   : WL f16 [k][l-1][n*64 + m]                              (8 KB/layer/k)
//   [147456 .. 151552)  : b_eff f32 [k][l][n]
__global__ __launch_bounds__(128) void precompute_kernel(
    const float* __restrict__ latent_tokens, const float* __restrict__ token_embeddings,
    const float* __restrict__ h_W0, const float* __restrict__ h_b0,
    const float* __restrict__ h_ln_s0, const float* __restrict__ h_ln_b0,
    const float* __restrict__ w_W0, const float* __restrict__ w_b0,
    const float* __restrict__ bb_W0, const float* __restrict__ bb_b0,
    const float* __restrict__ h_W, const float* __restrict__ h_b,
    const float* __restrict__ h_ln_s, const float* __restrict__ h_ln_b,
    const float* __restrict__ w_W, const float* __restrict__ w_b,
    const float* __restrict__ bb_W, const float* __restrict__ bb_b,
    float* __restrict__ ws, int offBbytes)
{
    const int s = blockIdx.x;    // column-slice 0..31
    const int l = blockIdx.y;    // 0..7
    const int tid = threadIdx.x; // 0..127
    const int lane = tid & 63;
    const int warp = tid >> 6;   // 0..1 -> k

    __shared__ float s_chunk[2][128];
    __shared__ float s_h[2][64];

#pragma unroll
    for (int t = tid; t < 256; t += 128) {
        int k = t >> 7, m = t & 127;
        s_chunk[k][m] = (m < 64) ? latent_tokens[(k * 8 + l) * 64 + m]
                                 : token_embeddings[l * 64 + (m - 64)];
    }
    __syncthreads();

    const float* hW  = (l == 0) ? h_W0    : h_W    + (size_t)(l - 1) * 128 * 64;
    const float* hb  = (l == 0) ? h_b0    : h_b    + (l - 1) * 64;
    const float* hls = (l == 0) ? h_ln_s0 : h_ln_s + (l - 1) * 64;
    const float* hlb = (l == 0) ? h_ln_b0 : h_ln_b + (l - 1) * 64;

    {
        float a = hb[lane];
#pragma unroll 16
        for (int m = 0; m < 128; m++) a += s_chunk[warp][m] * hW[m * 64 + lane];
        float mu, rstd;
        ln_stats(a, mu, rstd);
        s_h[warp][lane] = fmaxf((a - mu) * rstd * hls[lane] + hlb[lane], 0.0f);
    }
    __syncthreads();

    const int n_in  = (l == 0) ? 126 : 64;
    const int nflat = 64 * n_in;
    const int slice = nflat / 32;        // 252 or 128
    const float* wW = (l == 0) ? w_W0 : w_W + (size_t)(l - 1) * 64 * 4096;
    const float* wb = (l == 0) ? w_b0 : w_b + (size_t)(l - 1) * 4096;
    _Float16* wsH = (_Float16*)ws;

    for (int o = s * slice + tid; o < s * slice + slice; o += 128) {
        float wbv = wb[o];
        float a0 = wbv, a1 = wbv;
#pragma unroll 16
        for (int j = 0; j < 64; j++) {
            float w = wW[(size_t)j * nflat + o];
            a0 += s_h[0][j] * w;
            a1 += s_h[1][j] * w;
        }
        int n = o / n_in, m = o - n * n_in;
        if (l == 0) {                                // u16 idx: k*8192 + n*128 + m
            wsH[n * 128 + m]        = (_Float16)a0;
            wsH[8192 + n * 128 + m] = (_Float16)a1;
        } else {                                     // 16384 + (k*7+l-1)*4096 + n*64 + m
            _Float16* b0p = wsH + 16384 + (size_t)(l - 1) * 4096;
            b0p[n * 64 + m]            = (_Float16)a0;
            b0p[7 * 4096 + n * 64 + m] = (_Float16)a1;
        }
    }

    if (l == 0 && s == 0) {              // zero pads m=126,127 for both k
        int n = tid >> 1, c = tid & 1;
        wsH[n * 128 + 126 + c] = (_Float16)0.0f;
        wsH[8192 + n * 128 + 126 + c] = (_Float16)0.0f;
    }

    if (s == 0) {
        const float* bW  = (l == 0) ? bb_W0 : bb_W + (size_t)(l - 1) * 64 * 64;
        const float* bb_ = (l == 0) ? bb_b0 : bb_b + (l - 1) * 64;
        float a = bb_[lane];
#pragma unroll 16
        for (int j = 0; j < 64; j++) a += s_h[warp][j] * bW[j * 64 + lane];
        ((float*)((char*)ws + offBbytes))[(warp * 8 + l) * 64 + lane] = a;
    }
}

// One wave = 4 rays; lane = neuron. Weights f16, MAC = readlane(packed pair) + v_dot2.
// Layer-granularity double buffer in NAMED uint4 regs (no arrays -> no scratch).
#define MC1(wc, pp) \
    accq0 = dot2u(wc, rlu(pk0, (pp)), accq0); \
    accq1 = dot2u(wc, rlu(pk1, (pp)), accq1); \
    accq2 = dot2u(wc, rlu(pk2, (pp)), accq2); \
    accq3 = dot2u(wc, rlu(pk3, (pp)), accq3);
#define MACCH(W, P0) { uint4 _w = (W); MC1(_w.x, (P0)) MC1(_w.y, (P0)+1) MC1(_w.z, (P0)+2) MC1(_w.w, (P0)+3) }
#define MACLAYER_A  MACCH(A0,0) MACCH(A1,4) MACCH(A2,8)  MACCH(A3,12) MACCH(A4,16) MACCH(A5,20) MACCH(A6,24) MACCH(A7,28)
#define MACLAYER_B  MACCH(B0,0) MACCH(B1,4) MACCH(B2,8)  MACCH(B3,12) MACCH(B4,16) MACCH(B5,20) MACCH(B6,24) MACCH(B7,28)
#define MACLAYER_B32 MACCH(B0,32) MACCH(B1,36) MACCH(B2,40) MACCH(B3,44) MACCH(B4,48) MACCH(B5,52) MACCH(B6,56) MACCH(B7,60)
#define LOAD_A(p) A0=(p)[0]; A1=(p)[1]; A2=(p)[2]; A3=(p)[3]; A4=(p)[4]; A5=(p)[5]; A6=(p)[6]; A7=(p)[7];
#define LOAD_B(p) B0=(p)[0]; B1=(p)[1]; B2=(p)[2]; B3=(p)[3]; B4=(p)[4]; B5=(p)[5]; B6=(p)[6]; B7=(p)[7];
#define BIAS(v)  accq0=(v); accq1=(v); accq2=(v); accq3=(v);
#define LNQ(aq, pq, S, B) { float mu, rstd; ln_stats(aq, mu, rstd); \
    aq = fmaxf((aq - mu) * rstd * (S) + (B), 0.0f); \
    pq = pkact(bpermf(pa0, aq), bpermf(pa1, aq)); }
#define LNP(S, B) LNQ(accq0, pk0, S, B) LNQ(accq1, pk1, S, B) LNQ(accq2, pk2, S, B) LNQ(accq3, pk3, S, B)

__global__ __launch_bounds__(256, 2) void forward_kernel(
    const float* __restrict__ rays,
    const float* __restrict__ ln_s0, const float* __restrict__ ln_b0,
    const float* __restrict__ ln_s, const float* __restrict__ ln_b,
    const float* __restrict__ rgb_W, const float* __restrict__ rgb_b,
    const float* __restrict__ ws, int offBbytes,
    float* __restrict__ out, int K, int P)
{
    const int warp = threadIdx.x >> 6;
    const int lane = threadIdx.x & 63;
    const int total = K * P;
    const int r0 = (blockIdx.x * 4 + warp) * 4;
    if (r0 >= total) return;
    const int k = r0 / P;                       // uniform per wave (P % 16 == 0)

    const char* wsB = (const char*)ws;
    const uint4* row0 = (const uint4*)(wsB + (size_t)k * 16384 + lane * 256);
    const uint4* rowL = (const uint4*)(wsB + 32768 + (size_t)k * 57344 + lane * 128);
    const float* beff = (const float*)(wsB + offBbytes) + k * 512;

    // weight pipeline first: all 16 chunks of layer 0 (m 0..127, f16 pairs)
    uint4 A0,A1,A2,A3,A4,A5,A6,A7, B0,B1,B2,B3,B4,B5,B6,B7;
    LOAD_A(row0); LOAD_B(row0 + 8);

    // prefetch all scalars (biases + LN params) while weights fly
    float be[8];
#pragma unroll
    for (int i = 0; i < 8; i++) be[i] = beff[i * 64 + lane];
    float s0v = ln_s0[lane], b0v = ln_b0[lane];
    float sl[7], bl[7];
#pragma unroll
    for (int i = 0; i < 7; i++) { sl[i] = ln_s[i * 64 + lane]; bl[i] = ln_b[i * 64 + lane]; }

    const int pa0 = ((2 * lane) & 63) << 2;     // bpermute byte addrs for packing
    const int pa1 = ((2 * lane + 1) & 63) << 2;

    // posenc directly in packed layout: lane p holds elements (2p, 2p+1)
    uint pk0, pk1, pk2, pk3;
    {
        const int e0 = 2 * lane, e1 = 2 * lane + 1;
#pragma unroll
        for (int q = 0; q < 4; q++) {
            int r = r0 + q; if (r > total - 1) r = total - 1;
            float o0 = rays[r * 6 + 0], o1 = rays[r * 6 + 1], o2 = rays[r * 6 + 2];
            float d0 = rays[r * 6 + 3], d1 = rays[r * 6 + 4], d2 = rays[r * 6 + 5];
            float pl[6];
            pl[0] = d0; pl[1] = d1; pl[2] = d2;
            pl[3] = o1 * d2 - o2 * d1;
            pl[4] = o2 * d0 - o0 * d2;
            pl[5] = o0 * d1 - o1 * d0;
            float v0 = (e0 < 126) ? posenc_elem(pl, e0) : 0.0f;
            float v1 = (e1 < 126) ? posenc_elem(pl, e1) : 0.0f;
            uint p = pkact(v0, v1);
            if (q == 0) pk0 = p; else if (q == 1) pk1 = p; else if (q == 2) pk2 = p; else pk3 = p;
        }
    }

    float accq0, accq1, accq2, accq3;

    // ----- layer 0 (126 m, pairs 0..63; pads are zero) -----
    BIAS(be[0]);
    MACLAYER_A;                 // pairs 0..31 (m 0..63)
    LOAD_A(rowL);               // layer 1 -> A (in flight under MAC-B + LN)
    MACLAYER_B32;               // pairs 32..63 (m 64..127)
    LNP(s0v, b0v);

    // ----- layers 1..7, ping-pong A/B; next layer's loads issue mid-layer -----
    BIAS(be[1]); MACLAYER_A; LOAD_B(rowL + 512);  LNP(sl[0], bl[0]);   // L1 (A), load L2
    BIAS(be[2]); MACLAYER_B; LOAD_A(rowL + 1024); LNP(sl[1], bl[1]);   // L2 (B), load L3
    BIAS(be[3]); MACLAYER_A; LOAD_B(rowL + 1536); LNP(sl[2], bl[2]);   // L3 (A), load L4
    BIAS(be[4]); MACLAYER_B; LOAD_A(rowL + 2048); LNP(sl[3], bl[3]);   // L4 (B), load L5
    BIAS(be[5]); MACLAYER_A; LOAD_B(rowL + 2560); LNP(sl[4], bl[4]);   // L5 (A), load L6
    BIAS(be[6]); MACLAYER_B; LOAD_A(rowL + 3072); LNP(sl[5], bl[5]);   // L6 (B), load L7
    BIAS(be[7]); MACLAYER_A;                      LNP(sl[6], bl[6]);   // L7 (A)

    // rgb head: rgb_W (64,3) row-major; accq* hold final activations
    float w0 = rgb_W[lane * 3 + 0], w1 = rgb_W[lane * 3 + 1], w2 = rgb_W[lane * 3 + 2];
    float b0 = rgb_b[0], b1 = rgb_b[1], b2 = rgb_b[2];
#pragma unroll
    for (int q = 0; q < 4; q++) {
        float a = (q == 0) ? accq0 : (q == 1) ? accq1 : (q == 2) ? accq2 : accq3;
        float c0 = wave_sum64(a * w0);
        float c1 = wave_sum64(a * w1);
        float c2 = wave_sum64(a * w2);
        if (lane == 0 && r0 + q < total) {
            out[(r0 + q) * 3 + 0] = 1.0f / (1.0f + expf(-(c0 + b0)));
            out[(r0 + q) * 3 + 1] = 1.0f / (1.0f + expf(-(c1 + b1)));
            out[(r0 + q) * 3 + 2] = 1.0f / (1.0f + expf(-(c2 + b2)));
        }
    }
}

extern "C" void kernel_launch(void* const* d_in, const int* in_sizes, int n_in,
                              void* d_out, int out_size, void* d_ws, size_t ws_size,
                              hipStream_t stream) {
    const float* rays    = (const float*)d_in[0];
    const float* latent  = (const float*)d_in[1];
    const float* tok_emb = (const float*)d_in[2];
    const float* h_W0    = (const float*)d_in[3];
    const float* h_b0    = (const float*)d_in[4];
    const float* h_ln_s0 = (const float*)d_in[5];
    const float* h_ln_b0 = (const float*)d_in[6];
    const float* w_W0    = (const float*)d_in[7];
    const float* w_b0    = (const float*)d_in[8];
    const float* bb_W0   = (const float*)d_in[9];
    const float* bb_b0   = (const float*)d_in[10];
    const float* ln_s0   = (const float*)d_in[11];
    const float* ln_b0   = (const float*)d_in[12];
    const float* h_W     = (const float*)d_in[13];
    const float* h_b     = (const float*)d_in[14];
    const float* h_ln_s  = (const float*)d_in[15];
    const float* h_ln_b  = (const float*)d_in[16];
    const float* w_W     = (const float*)d_in[17];
    const float* w_b     = (const float*)d_in[18];
    const float* bb_W    = (const float*)d_in[19];
    const float* bb_b    = (const float*)d_in[20];
    const float* ln_s    = (const float*)d_in[21];
    const float* ln_b    = (const float*)d_in[22];
    const float* rgb_W   = (const float*)d_in[23];
    const float* rgb_b   = (const float*)d_in[24];
    float* out = (float*)d_out;

    const int K = in_sizes[1] / (8 * 64);      // K==2 in dataset
    const int P = in_sizes[0] / (6 * K);
    const int offBbytes = K * 16384 + K * 7 * 8192;   // 147456 for K=2

    float* ws = (float*)d_ws;

    dim3 pgrid(32, 8);
    precompute_kernel<<<pgrid, 128, 0, stream>>>(
        latent, tok_emb, h_W0, h_b0, h_ln_s0, h_ln_b0, w_W0, w_b0, bb_W0, bb_b0,
        h_W, h_b, h_ln_s, h_ln_b, w_W, w_b, bb_W, bb_b, ws, offBbytes);

    const int total = K * P;
    const int blocks = (total + 15) / 16;      // 4 waves x 4 rays per block
    forward_kernel<<<blocks, 256, 0, stream>>>(
        rays, ln_s0, ln_b0, ln_s, ln_b, rgb_W, rgb_b,
        ws, offBbytes, out, K, P);
}

// Round 9
// 132.527 us; speedup vs baseline: 1.2498x; 1.0790x over previous
//
#include <hip/hip_runtime.h>
#include <math.h>

#define EPSF 1e-6f
typedef unsigned int uint;
typedef _Float16 f16x8v __attribute__((ext_vector_type(8)));
typedef float f32x4v __attribute__((ext_vector_type(4)));
typedef _Float16 f16x2 __attribute__((ext_vector_type(2)));
typedef __fp16 h16x2 __attribute__((ext_vector_type(2)));

__device__ __forceinline__ uint pkact(float lo, float hi) {
#if __has_builtin(__builtin_amdgcn_cvt_pkrtz)
    h16x2 p = __builtin_amdgcn_cvt_pkrtz(lo, hi);
    return __builtin_bit_cast(uint, p);
#else
    f16x2 p; p.x = (_Float16)lo; p.y = (_Float16)hi;
    return __builtin_bit_cast(uint, p);
#endif
}

__device__ __forceinline__ f32x4v mfma16(uint4 a, uint4 b, f32x4v c) {
    return __builtin_amdgcn_mfma_f32_16x16x32_f16(
        __builtin_bit_cast(f16x8v, a), __builtin_bit_cast(f16x8v, b), c, 0, 0, 0);
}

// reduce two values across the 16-lane group (lane bits 0..3)
__device__ __forceinline__ void red16_2(float& x, float& y) {
#pragma unroll
    for (int off = 1; off < 16; off <<= 1) {
        x += __shfl_xor(x, off, 64);
        y += __shfl_xor(y, off, 64);
    }
}

// single-pass LN stats over 64 lanes (used by precompute)
__device__ __forceinline__ void ln_stats(float a, float& mu, float& rstd) {
    float s1 = a, s2 = a * a;
#pragma unroll
    for (int off = 32; off > 0; off >>= 1) {
        s1 += __shfl_xor(s1, off, 64);
        s2 += __shfl_xor(s2, off, 64);
    }
    mu = s1 * (1.0f / 64.0f);
    float var = fmaxf(s2 * (1.0f / 64.0f) - mu * mu, 0.0f);
    rstd = rsqrtf(var + EPSF);
}

// posenc element e in [0,126)
__device__ __forceinline__ float posenc_elem(const float* pl, int e) {
    if (e < 6) return pl[e];
    int t = e - 6;
    int j = t / 6;
    int i = t - j * 6;
    int jm = (j < 10) ? j : (j - 10);
    float arg = pl[i] * (float)(1 << jm);
    if (j >= 10) arg += 1.5707963705062866f;
    return sinf(arg);
}

// ws layout (BYTES), K==2:
//   [0 .. 32768)        : W0 f16 [k][n*128 + m], m in [0,126), m=126,127 zeroed
//   [32768 .. 147456)   : WL f16 [k][l-1][n*64 + m]
//   [147456 .. 151552)  : b_eff f32 [k][l][n]
__global__ __launch_bounds__(128) void precompute_kernel(
    const float* __restrict__ latent_tokens, const float* __restrict__ token_embeddings,
    const float* __restrict__ h_W0, const float* __restrict__ h_b0,
    const float* __restrict__ h_ln_s0, const float* __restrict__ h_ln_b0,
    const float* __restrict__ w_W0, const float* __restrict__ w_b0,
    const float* __restrict__ bb_W0, const float* __restrict__ bb_b0,
    const float* __restrict__ h_W, const float* __restrict__ h_b,
    const float* __restrict__ h_ln_s, const float* __restrict__ h_ln_b,
    const float* __restrict__ w_W, const float* __restrict__ w_b,
    const float* __restrict__ bb_W, const float* __restrict__ bb_b,
    float* __restrict__ ws, int offBbytes)
{
    const int s = blockIdx.x;    // column-slice 0..31
    const int l = blockIdx.y;    // 0..7
    const int tid = threadIdx.x; // 0..127
    const int lane = tid & 63;
    const int warp = tid >> 6;   // 0..1 -> k

    __shared__ float s_chunk[2][128];
    __shared__ float s_h[2][64];

#pragma unroll
    for (int t = tid; t < 256; t += 128) {
        int k = t >> 7, m = t & 127;
        s_chunk[k][m] = (m < 64) ? latent_tokens[(k * 8 + l) * 64 + m]
                                 : token_embeddings[l * 64 + (m - 64)];
    }
    __syncthreads();

    const float* hW  = (l == 0) ? h_W0    : h_W    + (size_t)(l - 1) * 128 * 64;
    const float* hb  = (l == 0) ? h_b0    : h_b    + (l - 1) * 64;
    const float* hls = (l == 0) ? h_ln_s0 : h_ln_s + (l - 1) * 64;
    const float* hlb = (l == 0) ? h_ln_b0 : h_ln_b + (l - 1) * 64;

    {
        float a = hb[lane];
#pragma unroll 16
        for (int m = 0; m < 128; m++) a += s_chunk[warp][m] * hW[m * 64 + lane];
        float mu, rstd;
        ln_stats(a, mu, rstd);
        s_h[warp][lane] = fmaxf((a - mu) * rstd * hls[lane] + hlb[lane], 0.0f);
    }
    __syncthreads();

    const int n_in  = (l == 0) ? 126 : 64;
    const int nflat = 64 * n_in;
    const int slice = nflat / 32;        // 252 or 128
    const float* wW = (l == 0) ? w_W0 : w_W + (size_t)(l - 1) * 64 * 4096;
    const float* wb = (l == 0) ? w_b0 : w_b + (size_t)(l - 1) * 4096;
    _Float16* wsH = (_Float16*)ws;

    for (int o = s * slice + tid; o < s * slice + slice; o += 128) {
        float wbv = wb[o];
        float a0 = wbv, a1 = wbv;
#pragma unroll 16
        for (int j = 0; j < 64; j++) {
            float w = wW[(size_t)j * nflat + o];
            a0 += s_h[0][j] * w;
            a1 += s_h[1][j] * w;
        }
        int n = o / n_in, m = o - n * n_in;
        if (l == 0) {
            wsH[n * 128 + m]        = (_Float16)a0;
            wsH[8192 + n * 128 + m] = (_Float16)a1;
        } else {
            _Float16* b0p = wsH + 16384 + (size_t)(l - 1) * 4096;
            b0p[n * 64 + m]            = (_Float16)a0;
            b0p[7 * 4096 + n * 64 + m] = (_Float16)a1;
        }
    }

    if (l == 0 && s == 0) {              // zero pads m=126,127 for both k
        int n = tid >> 1, c = tid & 1;
        wsH[n * 128 + 126 + c] = (_Float16)0.0f;
        wsH[8192 + n * 128 + 126 + c] = (_Float16)0.0f;
    }

    if (s == 0) {
        const float* bW  = (l == 0) ? bb_W0 : bb_W + (size_t)(l - 1) * 64 * 64;
        const float* bb_ = (l == 0) ? bb_b0 : bb_b + (l - 1) * 64;
        float a = bb_[lane];
#pragma unroll 16
        for (int j = 0; j < 64; j++) a += s_h[warp][j] * bW[j * 64 + lane];
        ((float*)((char*)ws + offBbytes))[(warp * 8 + l) * 64 + lane] = a;
    }
}

// MFMA forward: 1 wave per block, 16 rays per wave.
// A = acts (16 rays x K) from wave-private LDS tile; B = weight frags from ws
// (natural [n][m] f16 rows ARE the B fragment layout: lane n=t*16+(lane&15),
//  elems k = kc*32 + (lane>>4)*8 + j). C layout: col=lane&15 (n), row=quad*4+e (ray).
// LN per ray = 16-lane xor-reduce over the row. No barriers anywhere.
__global__ __launch_bounds__(64) void forward_kernel(
    const float* __restrict__ rays,
    const float* __restrict__ ln_s0, const float* __restrict__ ln_b0,
    const float* __restrict__ ln_s, const float* __restrict__ ln_b,
    const float* __restrict__ rgb_W, const float* __restrict__ rgb_b,
    const float* __restrict__ ws, int offBbytes,
    float* __restrict__ out, int K, int P)
{
    __shared__ _Float16 acts[16 * 136];   // 16 rays x (<=128 k, stride 136 breaks bank stride)
    const int lane = threadIdx.x;
    const int quad = lane >> 4;           // 0..3
    const int c    = lane & 15;           // n-within-tile / A-row (ray)
    const int total = K * P;
    const int r0 = blockIdx.x * 16;
    if (r0 >= total) return;
    const int k = r0 / P;                 // uniform per block (P % 16 == 0)

    const _Float16* W0 = (const _Float16*)ws + (size_t)k * 8192;
    const _Float16* WL = (const _Float16*)ws + 16384 + (size_t)k * 28672;
    const float* beff = (const float*)((const char*)ws + offBbytes) + k * 512;

    // ---- issue layer-0 B-frag loads first (16 x dwordx4) ----
    uint4 B0f[4][4];
#pragma unroll
    for (int t = 0; t < 4; t++)
#pragma unroll
        for (int kc = 0; kc < 4; kc++)
            B0f[t][kc] = *(const uint4*)(W0 + (t * 16 + c) * 128 + kc * 32 + quad * 8);

    // ---- posenc -> LDS (f16, packed); lane handles ray=lane>>2, elems (lane&3)*32.. ----
    {
        int rr = lane >> 2;
        int r = r0 + rr; if (r > total - 1) r = total - 1;
        float o0 = rays[r * 6 + 0], o1 = rays[r * 6 + 1], o2 = rays[r * 6 + 2];
        float d0 = rays[r * 6 + 3], d1 = rays[r * 6 + 4], d2 = rays[r * 6 + 5];
        float pl[6];
        pl[0] = d0; pl[1] = d1; pl[2] = d2;
        pl[3] = o1 * d2 - o2 * d1;
        pl[4] = o2 * d0 - o0 * d2;
        pl[5] = o0 * d1 - o1 * d0;
        int e0 = (lane & 3) * 32;
        uint pk[16];
#pragma unroll
        for (int i = 0; i < 16; i++) {
            int ea = e0 + 2 * i;
            float va = (ea < 126) ? posenc_elem(pl, ea) : 0.0f;
            float vb = (ea + 1 < 126) ? posenc_elem(pl, ea + 1) : 0.0f;
            pk[i] = pkact(va, vb);
        }
        uint4* dst = (uint4*)(acts + rr * 136 + e0);
#pragma unroll
        for (int i = 0; i < 4; i++)
            dst[i] = make_uint4(pk[4 * i], pk[4 * i + 1], pk[4 * i + 2], pk[4 * i + 3]);
    }

    // ---- prefetch layer-1 B-frags + layer-0 params ----
    uint4 Bf[2][4][2];
#pragma unroll
    for (int t = 0; t < 4; t++)
#pragma unroll
        for (int kc = 0; kc < 2; kc++)
            Bf[1][t][kc] = *(const uint4*)(WL + (t * 16 + c) * 64 + kc * 32 + quad * 8);

    float ga[4], be_[4];
    f32x4v C[4];
#pragma unroll
    for (int t = 0; t < 4; t++) {
        int n = t * 16 + c;
        ga[t] = ln_s0[n]; be_[t] = ln_b0[n];
        float bv = beff[n];
        C[t] = (f32x4v){bv, bv, bv, bv};
    }

    // ---- layer 0: K=128 (4 MFMA k-chunks) ----
    {
        uint4 A0[4];
#pragma unroll
        for (int kc = 0; kc < 4; kc++)
            A0[kc] = *(const uint4*)(acts + c * 136 + kc * 32 + quad * 8);
#pragma unroll
        for (int t = 0; t < 4; t++)
#pragma unroll
            for (int kc = 0; kc < 4; kc++)
                C[t] = mfma16(A0[kc], B0f[t][kc], C[t]);
    }

    float alast[4][4];   // [t][e], only set at l==7

    // LN(l=0) + store, then layers 1..7
#pragma unroll
    for (int e = 0; e < 4; e++) {
        float s1 = C[0][e] + C[1][e] + C[2][e] + C[3][e];
        float s2 = C[0][e]*C[0][e] + C[1][e]*C[1][e] + C[2][e]*C[2][e] + C[3][e]*C[3][e];
        red16_2(s1, s2);
        float mu = s1 * (1.0f / 64.0f);
        float var = fmaxf(s2 * (1.0f / 64.0f) - mu * mu, 0.0f);
        float rstd = rsqrtf(var + EPSF);
        int row = quad * 4 + e;
#pragma unroll
        for (int t = 0; t < 4; t++) {
            float a = fmaxf((C[t][e] - mu) * rstd * ga[t] + be_[t], 0.0f);
            acts[row * 136 + t * 16 + c] = (_Float16)a;
        }
    }

#pragma unroll
    for (int l = 1; l < 8; l++) {
        uint4 A[2];
        A[0] = *(const uint4*)(acts + c * 136 + quad * 8);
        A[1] = *(const uint4*)(acts + c * 136 + 32 + quad * 8);
        if (l < 7) {     // prefetch layer l+1 weights into the other buffer
            const _Float16* Wn = WL + (size_t)l * 4096;
#pragma unroll
            for (int t = 0; t < 4; t++)
#pragma unroll
                for (int kc = 0; kc < 2; kc++)
                    Bf[(l + 1) & 1][t][kc] = *(const uint4*)(Wn + (t * 16 + c) * 64 + kc * 32 + quad * 8);
        }
        float g2[4], b2[4];
#pragma unroll
        for (int t = 0; t < 4; t++) {
            int n = t * 16 + c;
            g2[t] = ln_s[(l - 1) * 64 + n];
            b2[t] = ln_b[(l - 1) * 64 + n];
            float bv = beff[l * 64 + n];
            C[t] = (f32x4v){bv, bv, bv, bv};
        }
#pragma unroll
        for (int t = 0; t < 4; t++)
#pragma unroll
            for (int kc = 0; kc < 2; kc++)
                C[t] = mfma16(A[kc], Bf[l & 1][t][kc], C[t]);

#pragma unroll
        for (int e = 0; e < 4; e++) {
            float s1 = C[0][e] + C[1][e] + C[2][e] + C[3][e];
            float s2 = C[0][e]*C[0][e] + C[1][e]*C[1][e] + C[2][e]*C[2][e] + C[3][e]*C[3][e];
            red16_2(s1, s2);
            float mu = s1 * (1.0f / 64.0f);
            float var = fmaxf(s2 * (1.0f / 64.0f) - mu * mu, 0.0f);
            float rstd = rsqrtf(var + EPSF);
            int row = quad * 4 + e;
#pragma unroll
            for (int t = 0; t < 4; t++) {
                float a = fmaxf((C[t][e] - mu) * rstd * g2[t] + b2[t], 0.0f);
                if (l < 7) acts[row * 136 + t * 16 + c] = (_Float16)a;
                else       alast[t][e] = a;
            }
        }
    }

    // ---- rgb head: per ray dot(acts, rgb_W[:,c]) via group reduce ----
    float w0_[4], w1_[4], w2_[4];
#pragma unroll
    for (int t = 0; t < 4; t++) {
        int n = t * 16 + c;
        w0_[t] = rgb_W[n * 3 + 0];
        w1_[t] = rgb_W[n * 3 + 1];
        w2_[t] = rgb_W[n * 3 + 2];
    }
    float rb0 = rgb_b[0], rb1 = rgb_b[1], rb2 = rgb_b[2];
#pragma unroll
    for (int e = 0; e < 4; e++) {
        float p0 = alast[0][e]*w0_[0] + alast[1][e]*w0_[1] + alast[2][e]*w0_[2] + alast[3][e]*w0_[3];
        float p1 = alast[0][e]*w1_[0] + alast[1][e]*w1_[1] + alast[2][e]*w1_[2] + alast[3][e]*w1_[3];
        float p2 = alast[0][e]*w2_[0] + alast[1][e]*w2_[1] + alast[2][e]*w2_[2] + alast[3][e]*w2_[3];
#pragma unroll
        for (int off = 1; off < 16; off <<= 1) {
            p0 += __shfl_xor(p0, off, 64);
            p1 += __shfl_xor(p1, off, 64);
            p2 += __shfl_xor(p2, off, 64);
        }
        int r = r0 + quad * 4 + e;
        if (c < 3 && r < total) {
            float p  = (c == 0) ? p0 : (c == 1) ? p1 : p2;
            float bb = (c == 0) ? rb0 : (c == 1) ? rb1 : rb2;
            out[r * 3 + c] = 1.0f / (1.0f + expf(-(p + bb)));
        }
    }
}

extern "C" void kernel_launch(void* const* d_in, const int* in_sizes, int n_in,
                              void* d_out, int out_size, void* d_ws, size_t ws_size,
                              hipStream_t stream) {
    const float* rays    = (const float*)d_in[0];
    const float* latent  = (const float*)d_in[1];
    const float* tok_emb = (const float*)d_in[2];
    const float* h_W0    = (const float*)d_in[3];
    const float* h_b0    = (const float*)d_in[4];
    const float* h_ln_s0 = (const float*)d_in[5];
    const float* h_ln_b0 = (const float*)d_in[6];
    const float* w_W0    = (const float*)d_in[7];
    const float* w_b0    = (const float*)d_in[8];
    const float* bb_W0   = (const float*)d_in[9];
    const float* bb_b0   = (const float*)d_in[10];
    const float* ln_s0   = (const float*)d_in[11];
    const float* ln_b0   = (const float*)d_in[12];
    const float* h_W     = (const float*)d_in[13];
    const float* h_b     = (const float*)d_in[14];
    const float* h_ln_s  = (const float*)d_in[15];
    const float* h_ln_b  = (const float*)d_in[16];
    const float* w_W     = (const float*)d_in[17];
    const float* w_b     = (const float*)d_in[18];
    const float* bb_W    = (const float*)d_in[19];
    const float* bb_b    = (const float*)d_in[20];
    const float* ln_s    = (const float*)d_in[21];
    const float* ln_b    = (const float*)d_in[22];
    const float* rgb_W   = (const float*)d_in[23];
    const float* rgb_b   = (const float*)d_in[24];
    float* out = (float*)d_out;

    const int K = in_sizes[1] / (8 * 64);      // K==2 in dataset
    const int P = in_sizes[0] / (6 * K);
    const int offBbytes = K * 16384 + K * 7 * 8192;   // 147456 for K=2

    float* ws = (float*)d_ws;

    dim3 pgrid(32, 8);
    precompute_kernel<<<pgrid, 128, 0, stream>>>(
        latent, tok_emb, h_W0, h_b0, h_ln_s0, h_ln_b0, w_W0, w_b0, bb_W0, bb_b0,
        h_W, h_b, h_ln_s, h_ln_b, w_W, w_b, bb_W, bb_b, ws, offBbytes);

    const int total = K * P;
    const int blocks = (total + 15) / 16;      // 1 wave x 16 rays per block
    forward_kernel<<<blocks, 64, 0, stream>>>(
        rays, ln_s0, ln_b0, ln_s, ln_b, rgb_W, rgb_b,
        ws, offBbytes, out, K, P);
}

// Round 10
// 131.004 us; speedup vs baseline: 1.2644x; 1.0116x over previous
//
#include <hip/hip_runtime.h>
#include <math.h>

#define EPSF 1e-6f
typedef unsigned int uint;
typedef _Float16 f16x8v __attribute__((ext_vector_type(8)));
typedef float f32x4v __attribute__((ext_vector_type(4)));
typedef _Float16 f16x2 __attribute__((ext_vector_type(2)));
typedef __fp16 h16x2 __attribute__((ext_vector_type(2)));

__device__ __forceinline__ uint pkact(float lo, float hi) {
#if __has_builtin(__builtin_amdgcn_cvt_pkrtz)
    h16x2 p = __builtin_amdgcn_cvt_pkrtz(lo, hi);
    return __builtin_bit_cast(uint, p);
#else
    f16x2 p; p.x = (_Float16)lo; p.y = (_Float16)hi;
    return __builtin_bit_cast(uint, p);
#endif
}

__device__ __forceinline__ f32x4v mfma16(uint4 a, uint4 b, f32x4v c) {
    return __builtin_amdgcn_mfma_f32_16x16x32_f16(
        __builtin_bit_cast(f16x8v, a), __builtin_bit_cast(f16x8v, b), c, 0, 0, 0);
}

// reduce two values across the 16-lane group (lane bits 0..3)
__device__ __forceinline__ void red16_2(float& x, float& y) {
#pragma unroll
    for (int off = 1; off < 16; off <<= 1) {
        x += __shfl_xor(x, off, 64);
        y += __shfl_xor(y, off, 64);
    }
}

// single-pass LN stats over 64 lanes (used by precompute)
__device__ __forceinline__ void ln_stats(float a, float& mu, float& rstd) {
    float s1 = a, s2 = a * a;
#pragma unroll
    for (int off = 32; off > 0; off >>= 1) {
        s1 += __shfl_xor(s1, off, 64);
        s2 += __shfl_xor(s2, off, 64);
    }
    mu = s1 * (1.0f / 64.0f);
    float var = fmaxf(s2 * (1.0f / 64.0f) - mu * mu, 0.0f);
    rstd = rsqrtf(var + EPSF);
}

// HW sin: input in revolutions; fract for range safety (|rev| up to ~400)
__device__ __forceinline__ float fast_sin_rev(float rev) {
    rev = rev - floorf(rev);
#if __has_builtin(__builtin_amdgcn_sinf)
    return __builtin_amdgcn_sinf(rev);
#else
    return __sinf(rev * 6.2831855f);
#endif
}

// posenc element e in [0,126): rev = x * 2^j * (1/2pi)  (+0.25 rev for cos)
__device__ __forceinline__ float posenc_elem(const float* pl, int e) {
    if (e < 6) return pl[e];
    int t = e - 6;
    int j = t / 6;
    int i = t - j * 6;
    int jm = (j < 10) ? j : (j - 10);
    float rev = pl[i] * ((float)(1 << jm) * 0.15915494f);  // exact pow2 scale of 1/2pi
    if (j >= 10) rev += 0.25f;
    return fast_sin_rev(rev);
}

// ws layout (BYTES), K==2:
//   [0 .. 32768)        : W0 f16 [k][n*128 + m], m in [0,126), m=126,127 zeroed
//   [32768 .. 147456)   : WL f16 [k][l-1][n*64 + m]
//   [147456 .. 151552)  : b_eff f32 [k][l][n]
__global__ __launch_bounds__(128) void precompute_kernel(
    const float* __restrict__ latent_tokens, const float* __restrict__ token_embeddings,
    const float* __restrict__ h_W0, const float* __restrict__ h_b0,
    const float* __restrict__ h_ln_s0, const float* __restrict__ h_ln_b0,
    const float* __restrict__ w_W0, const float* __restrict__ w_b0,
    const float* __restrict__ bb_W0, const float* __restrict__ bb_b0,
    const float* __restrict__ h_W, const float* __restrict__ h_b,
    const float* __restrict__ h_ln_s, const float* __restrict__ h_ln_b,
    const float* __restrict__ w_W, const float* __restrict__ w_b,
    const float* __restrict__ bb_W, const float* __restrict__ bb_b,
    float* __restrict__ ws, int offBbytes)
{
    const int s = blockIdx.x;    // column-slice 0..31
    const int l = blockIdx.y;    // 0..7
    const int tid = threadIdx.x; // 0..127
    const int lane = tid & 63;
    const int warp = tid >> 6;   // 0..1 -> k

    __shared__ float s_chunk[2][128];
    __shared__ float s_h[2][64];

#pragma unroll
    for (int t = tid; t < 256; t += 128) {
        int k = t >> 7, m = t & 127;
        s_chunk[k][m] = (m < 64) ? latent_tokens[(k * 8 + l) * 64 + m]
                                 : token_embeddings[l * 64 + (m - 64)];
    }
    __syncthreads();

    const float* hW  = (l == 0) ? h_W0    : h_W    + (size_t)(l - 1) * 128 * 64;
    const float* hb  = (l == 0) ? h_b0    : h_b    + (l - 1) * 64;
    const float* hls = (l == 0) ? h_ln_s0 : h_ln_s + (l - 1) * 64;
    const float* hlb = (l == 0) ? h_ln_b0 : h_ln_b + (l - 1) * 64;

    {
        float a = hb[lane];
#pragma unroll 32
        for (int m = 0; m < 128; m++) a += s_chunk[warp][m] * hW[m * 64 + lane];
        float mu, rstd;
        ln_stats(a, mu, rstd);
        s_h[warp][lane] = fmaxf((a - mu) * rstd * hls[lane] + hlb[lane], 0.0f);
    }
    __syncthreads();

    const int n_in  = (l == 0) ? 126 : 64;
    const int nflat = 64 * n_in;
    const int slice = nflat / 32;        // 252 or 128
    const float* wW = (l == 0) ? w_W0 : w_W + (size_t)(l - 1) * 64 * 4096;
    const float* wb = (l == 0) ? w_b0 : w_b + (size_t)(l - 1) * 4096;
    _Float16* wsH = (_Float16*)ws;

    for (int o = s * slice + tid; o < s * slice + slice; o += 128) {
        float wbv = wb[o];
        float a0 = wbv, a1 = wbv;
#pragma unroll 32
        for (int j = 0; j < 64; j++) {
            float w = wW[(size_t)j * nflat + o];
            a0 += s_h[0][j] * w;
            a1 += s_h[1][j] * w;
        }
        int n = o / n_in, m = o - n * n_in;
        if (l == 0) {
            wsH[n * 128 + m]        = (_Float16)a0;
            wsH[8192 + n * 128 + m] = (_Float16)a1;
        } else {
            _Float16* b0p = wsH + 16384 + (size_t)(l - 1) * 4096;
            b0p[n * 64 + m]            = (_Float16)a0;
            b0p[7 * 4096 + n * 64 + m] = (_Float16)a1;
        }
    }

    if (l == 0 && s == 0) {              // zero pads m=126,127 for both k
        int n = tid >> 1, c = tid & 1;
        wsH[n * 128 + 126 + c] = (_Float16)0.0f;
        wsH[8192 + n * 128 + 126 + c] = (_Float16)0.0f;
    }

    if (s == 0) {
        const float* bW  = (l == 0) ? bb_W0 : bb_W + (size_t)(l - 1) * 64 * 64;
        const float* bb_ = (l == 0) ? bb_b0 : bb_b + (l - 1) * 64;
        float a = bb_[lane];
#pragma unroll 32
        for (int j = 0; j < 64; j++) a += s_h[warp][j] * bW[j * 64 + lane];
        ((float*)((char*)ws + offBbytes))[(warp * 8 + l) * 64 + lane] = a;
    }
}

// MFMA forward: 1 wave per block, 16 rays per wave.
// A = acts (16 rays x K) from wave-private LDS tile; B = weight frags from ws
// (natural [n][m] f16 rows ARE the B fragment layout). C: col=lane&15, row=quad*4+e.
// All global loads issued BEFORE the posenc VALU chain so latency hides under it.
__global__ __launch_bounds__(64) void forward_kernel(
    const float* __restrict__ rays,
    const float* __restrict__ ln_s0, const float* __restrict__ ln_b0,
    const float* __restrict__ ln_s, const float* __restrict__ ln_b,
    const float* __restrict__ rgb_W, const float* __restrict__ rgb_b,
    const float* __restrict__ ws, int offBbytes,
    float* __restrict__ out, int K, int P)
{
    __shared__ _Float16 acts[16 * 136];   // 16 rays x (<=128 k), stride 136
    const int lane = threadIdx.x;
    const int quad = lane >> 4;           // 0..3
    const int c    = lane & 15;
    const int total = K * P;
    const int r0 = blockIdx.x * 16;
    if (r0 >= total) return;
    const int k = r0 / P;                 // uniform per block (P % 16 == 0)

    const _Float16* W0 = (const _Float16*)ws + (size_t)k * 8192;
    const _Float16* WL = (const _Float16*)ws + 16384 + (size_t)k * 28672;
    const float* beff = (const float*)((const char*)ws + offBbytes) + k * 512;

    // ---- 1. ray loads first (feed posenc) ----
    const int rr = lane >> 2;
    int rri = r0 + rr; if (rri > total - 1) rri = total - 1;
    float ro0 = rays[rri * 6 + 0], ro1 = rays[rri * 6 + 1], ro2 = rays[rri * 6 + 2];
    float rd0 = rays[rri * 6 + 3], rd1 = rays[rri * 6 + 4], rd2 = rays[rri * 6 + 5];

    // ---- 2. layer-0 B frags (16 x dwordx4) ----
    uint4 B0f[4][4];
#pragma unroll
    for (int t = 0; t < 4; t++)
#pragma unroll
        for (int kc = 0; kc < 4; kc++)
            B0f[t][kc] = *(const uint4*)(W0 + (t * 16 + c) * 128 + kc * 32 + quad * 8);

    // ---- 3. layer-1 B frags + all layer-0 params ----
    uint4 Bf[2][4][2];
#pragma unroll
    for (int t = 0; t < 4; t++)
#pragma unroll
        for (int kc = 0; kc < 2; kc++)
            Bf[1][t][kc] = *(const uint4*)(WL + (t * 16 + c) * 64 + kc * 32 + quad * 8);

    float ga[4], be_[4];
    f32x4v C[4];
#pragma unroll
    for (int t = 0; t < 4; t++) {
        int n = t * 16 + c;
        ga[t] = ln_s0[n]; be_[t] = ln_b0[n];
        float bv = beff[n];
        C[t] = (f32x4v){bv, bv, bv, bv};
    }

    // ---- 4. posenc (long VALU chain; all loads above in flight) ----
    {
        float pl[6];
        pl[0] = rd0; pl[1] = rd1; pl[2] = rd2;
        pl[3] = ro1 * rd2 - ro2 * rd1;
        pl[4] = ro2 * rd0 - ro0 * rd2;
        pl[5] = ro0 * rd1 - ro1 * rd0;
        int e0 = (lane & 3) * 32;
        uint pk[16];
#pragma unroll
        for (int i = 0; i < 16; i++) {
            int ea = e0 + 2 * i;
            float va = (ea < 126) ? posenc_elem(pl, ea) : 0.0f;
            float vb = (ea + 1 < 126) ? posenc_elem(pl, ea + 1) : 0.0f;
            pk[i] = pkact(va, vb);
        }
        uint4* dst = (uint4*)(acts + rr * 136 + e0);
#pragma unroll
        for (int i = 0; i < 4; i++)
            dst[i] = make_uint4(pk[4 * i], pk[4 * i + 1], pk[4 * i + 2], pk[4 * i + 3]);
    }

    // ---- layer 0: K=128 (4 MFMA k-chunks) ----
    {
        uint4 A0[4];
#pragma unroll
        for (int kc = 0; kc < 4; kc++)
            A0[kc] = *(const uint4*)(acts + c * 136 + kc * 32 + quad * 8);
#pragma unroll
        for (int t = 0; t < 4; t++)
#pragma unroll
            for (int kc = 0; kc < 4; kc++)
                C[t] = mfma16(A0[kc], B0f[t][kc], C[t]);
    }

    float alast[4][4];   // [t][e], set at l==7

    // LN(l=0) + store
#pragma unroll
    for (int e = 0; e < 4; e++) {
        float s1 = C[0][e] + C[1][e] + C[2][e] + C[3][e];
        float s2 = C[0][e]*C[0][e] + C[1][e]*C[1][e] + C[2][e]*C[2][e] + C[3][e]*C[3][e];
        red16_2(s1, s2);
        float mu = s1 * (1.0f / 64.0f);
        float var = fmaxf(s2 * (1.0f / 64.0f) - mu * mu, 0.0f);
        float rstd = rsqrtf(var + EPSF);
        int row = quad * 4 + e;
#pragma unroll
        for (int t = 0; t < 4; t++) {
            float a = fmaxf((C[t][e] - mu) * rstd * ga[t] + be_[t], 0.0f);
            acts[row * 136 + t * 16 + c] = (_Float16)a;
        }
    }

#pragma unroll
    for (int l = 1; l < 8; l++) {
        uint4 A[2];
        A[0] = *(const uint4*)(acts + c * 136 + quad * 8);
        A[1] = *(const uint4*)(acts + c * 136 + 32 + quad * 8);
        if (l < 7) {     // prefetch layer l+1 weights into the other buffer
            const _Float16* Wn = WL + (size_t)l * 4096;
#pragma unroll
            for (int t = 0; t < 4; t++)
#pragma unroll
                for (int kc = 0; kc < 2; kc++)
                    Bf[(l + 1) & 1][t][kc] = *(const uint4*)(Wn + (t * 16 + c) * 64 + kc * 32 + quad * 8);
        }
        float g2[4], b2[4];
#pragma unroll
        for (int t = 0; t < 4; t++) {
            int n = t * 16 + c;
            g2[t] = ln_s[(l - 1) * 64 + n];
            b2[t] = ln_b[(l - 1) * 64 + n];
            float bv = beff[l * 64 + n];
            C[t] = (f32x4v){bv, bv, bv, bv};
        }
#pragma unroll
        for (int t = 0; t < 4; t++)
#pragma unroll
            for (int kc = 0; kc < 2; kc++)
                C[t] = mfma16(A[kc], Bf[l & 1][t][kc], C[t]);

#pragma unroll
        for (int e = 0; e < 4; e++) {
            float s1 = C[0][e] + C[1][e] + C[2][e] + C[3][e];
            float s2 = C[0][e]*C[0][e] + C[1][e]*C[1][e] + C[2][e]*C[2][e] + C[3][e]*C[3][e];
            red16_2(s1, s2);
            float mu = s1 * (1.0f / 64.0f);
            float var = fmaxf(s2 * (1.0f / 64.0f) - mu * mu, 0.0f);
            float rstd = rsqrtf(var + EPSF);
            int row = quad * 4 + e;
#pragma unroll
            for (int t = 0; t < 4; t++) {
                float a = fmaxf((C[t][e] - mu) * rstd * g2[t] + b2[t], 0.0f);
                if (l < 7) acts[row * 136 + t * 16 + c] = (_Float16)a;
                else       alast[t][e] = a;
            }
        }
    }

    // ---- rgb head ----
    float w0_[4], w1_[4], w2_[4];
#pragma unroll
    for (int t = 0; t < 4; t++) {
        int n = t * 16 + c;
        w0_[t] = rgb_W[n * 3 + 0];
        w1_[t] = rgb_W[n * 3 + 1];
        w2_[t] = rgb_W[n * 3 + 2];
    }
    float rb0 = rgb_b[0], rb1 = rgb_b[1], rb2 = rgb_b[2];
#pragma unroll
    for (int e = 0; e < 4; e++) {
        float p0 = alast[0][e]*w0_[0] + alast[1][e]*w0_[1] + alast[2][e]*w0_[2] + alast[3][e]*w0_[3];
        float p1 = alast[0][e]*w1_[0] + alast[1][e]*w1_[1] + alast[2][e]*w1_[2] + alast[3][e]*w1_[3];
        float p2 = alast[0][e]*w2_[0] + alast[1][e]*w2_[1] + alast[2][e]*w2_[2] + alast[3][e]*w2_[3];
#pragma unroll
        for (int off = 1; off < 16; off <<= 1) {
            p0 += __shfl_xor(p0, off, 64);
            p1 += __shfl_xor(p1, off, 64);
            p2 += __shfl_xor(p2, off, 64);
        }
        int r = r0 + quad * 4 + e;
        if (c < 3 && r < total) {
            float p  = (c == 0) ? p0 : (c == 1) ? p1 : p2;
            float bb = (c == 0) ? rb0 : (c == 1) ? rb1 : rb2;
            out[r * 3 + c] = 1.0f / (1.0f + expf(-(p + bb)));
        }
    }
}

extern "C" void kernel_launch(void* const* d_in, const int* in_sizes, int n_in,
                              void* d_out, int out_size, void* d_ws, size_t ws_size,
                              hipStream_t stream) {
    const float* rays    = (const float*)d_in[0];
    const float* latent  = (const float*)d_in[1];
    const float* tok_emb = (const float*)d_in[2];
    const float* h_W0    = (const float*)d_in[3];
    const float* h_b0    = (const float*)d_in[4];
    const float* h_ln_s0 = (const float*)d_in[5];
    const float* h_ln_b0 = (const float*)d_in[6];
    const float* w_W0    = (const float*)d_in[7];
    const float* w_b0    = (const float*)d_in[8];
    const float* bb_W0   = (const float*)d_in[9];
    const float* bb_b0   = (const float*)d_in[10];
    const float* ln_s0   = (const float*)d_in[11];
    const float* ln_b0   = (const float*)d_in[12];
    const float* h_W     = (const float*)d_in[13];
    const float* h_b     = (const float*)d_in[14];
    const float* h_ln_s  = (const float*)d_in[15];
    const float* h_ln_b  = (const float*)d_in[16];
    const float* w_W     = (const float*)d_in[17];
    const float* w_b     = (const float*)d_in[18];
    const float* bb_W    = (const float*)d_in[19];
    const float* bb_b    = (const float*)d_in[20];
    const float* ln_s    = (const float*)d_in[21];
    const float* ln_b    = (const float*)d_in[22];
    const float* rgb_W   = (const float*)d_in[23];
    const float* rgb_b   = (const float*)d_in[24];
    float* out = (float*)d_out;

    const int K = in_sizes[1] / (8 * 64);      // K==2 in dataset
    const int P = in_sizes[0] / (6 * K);
    const int offBbytes = K * 16384 + K * 7 * 8192;   // 147456 for K=2

    float* ws = (float*)d_ws;

    dim3 pgrid(32, 8);
    precompute_kernel<<<pgrid, 128, 0, stream>>>(
        latent, tok_emb, h_W0, h_b0, h_ln_s0, h_ln_b0, w_W0, w_b0, bb_W0, bb_b0,
        h_W, h_b, h_ln_s, h_ln_b, w_W, w_b, bb_W, bb_b, ws, offBbytes);

    const int total = K * P;
    const int blocks = (total + 15) / 16;      // 1 wave x 16 rays per block
    forward_kernel<<<blocks, 64, 0, stream>>>(
        rays, ln_s0, ln_b0, ln_s, ln_b, rgb_W, rgb_b,
        ws, offBbytes, out, K, P);
}